// Round 3
// baseline (5174.034 us; speedup 1.0000x reference)
//
#include <hip/hip_runtime.h>

// Encoder: x[B,T] int32, hidden[B,U], emb[V,E], Wx[E,U], Wh[U,U], b[U]  -- ALL FLOAT32
// out = concat( output[B,T,U], state[B,U] )  float32
// B=64 T=512 U=1024 E=256
// Precision scheme: fp16 two-way split (hi + 2^11-scaled lo), 3 MFMA products
// => ~22-bit effective mantissa ~= f32-grade per-step error (~1e-7), needed because
// the tanh-RNN amplifies injected error ~2%/step over 512 steps.

#define B_ 64
#define T_ 512
#define U_ 1024
#define E_ 256
#define BTU_ (B_*T_*U_)
#define LO_SCALE 2048.0f
#define LO_INV   (1.0f/2048.0f)

typedef __attribute__((ext_vector_type(8))) _Float16 f16x8;  // MFMA A/B frag (4 VGPRs)
typedef __attribute__((ext_vector_type(4))) float f32x4;     // MFMA C/D frag

__device__ __forceinline__ void split16(float v, _Float16& hi, _Float16& lo) {
    hi = (_Float16)v;
    lo = (_Float16)((v - (float)hi) * LO_SCALE);   // scaled into fp16 normal range
}

// ---------------------------------------------------------------------------
// init: split f32 hidden into fp16 hi / scaled-lo planes (h_{-1})
// ---------------------------------------------------------------------------
__global__ void init_h(const float* __restrict__ hidden,
                       _Float16* __restrict__ hi, _Float16* __restrict__ lo)
{
    const int i = blockIdx.x * 256 + threadIdx.x;   // 256 x 256 = B*U
    _Float16 h, l;
    split16(hidden[i], h, l);
    hi[i] = h; lo[i] = l;
}

// ---------------------------------------------------------------------------
// Phase 1: xin[m][u] = emb[x[m]][:] @ Wx + b  (m = b*T + t), f32 -> out[m*U+u]
// fp16-split MFMA (hh + cross/2048). Grid (32,16) x 256.
// ---------------------------------------------------------------------------
__global__ __launch_bounds__(256, 1) void xin_gemm(
    const int* __restrict__ x, const float* __restrict__ emb,
    const float* __restrict__ Wx, const float* __restrict__ bias,
    float* __restrict__ out)
{
    const int tid  = threadIdx.x;
    const int wave = tid >> 6, lane = tid & 63;
    const int quad = lane >> 4, l15 = lane & 15;
    const int nbase  = blockIdx.y * 64;
    const int mouter = blockIdx.x * 1024;

    // B fragments: B[k][n], lane holds n=l15, k=quad*8+j (+32*ki). hi+lo = 256 VGPRs.
    f16x8 b1[4][8], b2[4][8];
#pragma unroll
    for (int nt = 0; nt < 4; ++nt) {
        const int col = nbase + nt*16 + l15;
#pragma unroll
        for (int ki = 0; ki < 8; ++ki) {
            const int kb = ki*32 + quad*8;
#pragma unroll
            for (int j = 0; j < 8; ++j) {
                _Float16 h, l;
                split16(Wx[(kb + j)*U_ + col], h, l);
                b1[nt][ki][j] = h; b2[nt][ki][j] = l;
            }
        }
    }
    float bv[4];
#pragma unroll
    for (int nt = 0; nt < 4; ++nt) bv[nt] = bias[nbase + nt*16 + l15];

    const f32x4 z4 = {0.f, 0.f, 0.f, 0.f};
    for (int mc = 0; mc < 8; ++mc) {
        const int mb0 = mouter + mc*128 + wave*32;
#pragma unroll
        for (int mt = 0; mt < 2; ++mt) {
            const int tok = x[mb0 + mt*16 + l15];
            const float* ap = emb + (size_t)tok*E_ + quad*8;
            f16x8 a1[8], a2[8];
#pragma unroll
            for (int ki = 0; ki < 8; ++ki) {
                const f32x4 v0 = *(const f32x4*)(ap + ki*32);
                const f32x4 v1 = *(const f32x4*)(ap + ki*32 + 4);
#pragma unroll
                for (int j = 0; j < 4; ++j) {
                    _Float16 h, l;
                    split16(v0[j], h, l); a1[ki][j]   = h; a2[ki][j]   = l;
                    split16(v1[j], h, l); a1[ki][j+4] = h; a2[ki][j+4] = l;
                }
            }
            f32x4 acc[4]  = {z4, z4, z4, z4};
            f32x4 accX[4] = {z4, z4, z4, z4};
#pragma unroll
            for (int ki = 0; ki < 8; ++ki)
#pragma unroll
                for (int nt = 0; nt < 4; ++nt) {
                    acc[nt]  = __builtin_amdgcn_mfma_f32_16x16x32_f16(a1[ki], b1[nt][ki], acc[nt], 0, 0, 0);
                    accX[nt] = __builtin_amdgcn_mfma_f32_16x16x32_f16(a1[ki], b2[nt][ki], accX[nt], 0, 0, 0);
                    accX[nt] = __builtin_amdgcn_mfma_f32_16x16x32_f16(a2[ki], b1[nt][ki], accX[nt], 0, 0, 0);
                }
            const int rowb = mb0 + mt*16 + quad*4;
#pragma unroll
            for (int nt = 0; nt < 4; ++nt) {
                const int col = nbase + nt*16 + l15;
#pragma unroll
                for (int r = 0; r < 4; ++r)
                    out[(size_t)(rowb + r)*U_ + col] = acc[nt][r] + LO_INV*accX[nt][r] + bv[nt];
            }
        }
    }
}

// ---------------------------------------------------------------------------
// Phase 2: persistent RNN scan, fp16-split recurrence (f32-grade accuracy).
// 4 batch-groups x 16 blocks (64 u-cols each). Wave w owns K-range [w*256,+256).
// Wh hi/lo frags persistent in 256 VGPRs. Per step: A hi/lo from global ping-pong
// planes, 96 MFMA (hh + 2 cross into scaled acc), LDS k-reduction, tanh, f32 store
// to d_out + split store to next h planes, flag barrier (release/acquire, agent).
// ---------------------------------------------------------------------------
__global__ __launch_bounds__(256, 1) void rnn_scan(
    const float* __restrict__ Wh,
    float* __restrict__ out,
    _Float16* __restrict__ hi0, _Float16* __restrict__ lo0,
    _Float16* __restrict__ hi1, _Float16* __restrict__ lo1,
    int* __restrict__ flags)
{
    const int tid  = threadIdx.x;
    const int w    = tid >> 6, lane = tid & 63;
    const int quad = lane >> 4, l15 = lane & 15;
    const int g    = blockIdx.x >> 4;    // batch group 0..3
    const int blk  = blockIdx.x & 15;    // column block 0..15
    const int bbase = g * 16;
    const int nb    = blk * 64;
    int* gflags = flags + g * 32;

    __shared__ __align__(16) float red[4][4][16][20];  // [wave][ntile][col][row(+pad)]

    // Persistent Wh fragments (split): k = w*256 + ki*32 + quad*8 + j, n = nb + nt*16 + l15
    f16x8 bh[4][8], bl[4][8];
#pragma unroll
    for (int nt = 0; nt < 4; ++nt) {
        const int col = nb + nt*16 + l15;
#pragma unroll
        for (int ki = 0; ki < 8; ++ki) {
            const int kb = w*256 + ki*32 + quad*8;
#pragma unroll
            for (int j = 0; j < 8; ++j) {
                _Float16 h, l;
                split16(Wh[(size_t)(kb + j)*U_ + col], h, l);
                bh[nt][ki][j] = h; bl[nt][ki][j] = l;
            }
        }
    }

    const int c  = tid >> 2;   // 0..63: column within block (combine phase)
    const int rq = tid & 3;    // row quad (combine phase)
    const f32x4 z4 = {0.f, 0.f, 0.f, 0.f};

    for (int t = 0; t < T_; ++t) {
        const _Float16* chi = (t & 1) ? hi1 : hi0;
        const _Float16* clo = (t & 1) ? lo1 : lo0;
        _Float16* nhi = (t & 1) ? hi0 : hi1;
        _Float16* nlo = (t & 1) ? lo0 : lo1;

        const size_t abase = (size_t)(bbase + l15)*U_ + w*256 + quad*8;
        f16x8 ah[8], al[8];
#pragma unroll
        for (int ki = 0; ki < 8; ++ki) {
            ah[ki] = *(const f16x8*)(chi + abase + ki*32);
            al[ki] = *(const f16x8*)(clo + abase + ki*32);
        }

        f32x4 acc[4]  = {z4, z4, z4, z4};
        f32x4 accX[4] = {z4, z4, z4, z4};
#pragma unroll
        for (int ki = 0; ki < 8; ++ki)
#pragma unroll
            for (int nt = 0; nt < 4; ++nt) {
                acc[nt]  = __builtin_amdgcn_mfma_f32_16x16x32_f16(ah[ki], bh[nt][ki], acc[nt], 0, 0, 0);
                accX[nt] = __builtin_amdgcn_mfma_f32_16x16x32_f16(ah[ki], bl[nt][ki], accX[nt], 0, 0, 0);
                accX[nt] = __builtin_amdgcn_mfma_f32_16x16x32_f16(al[ki], bh[nt][ki], accX[nt], 0, 0, 0);
            }

#pragma unroll
        for (int nt = 0; nt < 4; ++nt) {
            f32x4 s = acc[nt] + LO_INV*accX[nt];
            *(f32x4*)&red[w][nt][l15][quad*4] = s;
        }
        __syncthreads();

        // Combine 4 k-partials, add xin (f32 in d_out), tanh, store
        f32x4 s0 = *(const f32x4*)&red[0][c>>4][c&15][rq*4];
        f32x4 s1 = *(const f32x4*)&red[1][c>>4][c&15][rq*4];
        f32x4 s2 = *(const f32x4*)&red[2][c>>4][c&15][rq*4];
        f32x4 s3 = *(const f32x4*)&red[3][c>>4][c&15][rq*4];
        f32x4 ss = (s0 + s1) + (s2 + s3);
        const int u = nb + c;
#pragma unroll
        for (int j = 0; j < 4; ++j) {
            const int b = bbase + rq*4 + j;
            const size_t xidx = ((size_t)b*T_ + t)*U_ + u;
            const float pre = out[xidx] + ss[j];
            const float h = tanhf(pre);
            out[xidx] = h;
            _Float16 hh, hl;
            split16(h, hh, hl);
            nhi[(size_t)b*U_ + u] = hh;
            nlo[(size_t)b*U_ + u] = hl;
            if (t == T_-1) out[(size_t)BTU_ + (size_t)b*U_ + u] = h;
        }
        __syncthreads();   // all h writes done before publishing

        if (t < T_-1) {
            if (w == 0) {
                if (lane == 0) {
                    __threadfence();
                    __hip_atomic_store(&gflags[blk], t + 1, __ATOMIC_RELEASE, __HIP_MEMORY_SCOPE_AGENT);
                }
                const int tgt = t + 1;
                for (;;) {
                    int v = __hip_atomic_load(&gflags[l15], __ATOMIC_ACQUIRE, __HIP_MEMORY_SCOPE_AGENT);
                    if (__all(v >= tgt)) break;
                    __builtin_amdgcn_s_sleep(2);
                }
            }
            __syncthreads();
        }
    }
}

extern "C" void kernel_launch(void* const* d_in, const int* in_sizes, int n_in,
                              void* d_out, int out_size, void* d_ws, size_t ws_size,
                              hipStream_t stream) {
    const int*   x      = (const int*)  d_in[0];
    const float* hidden = (const float*)d_in[1];
    const float* emb    = (const float*)d_in[2];
    const float* Wx     = (const float*)d_in[3];
    const float* Wh     = (const float*)d_in[4];
    const float* bias   = (const float*)d_in[5];
    float* out = (float*)d_out;

    char* ws = (char*)d_ws;
    int* flags = (int*)ws;                               // 4 groups x 32 ints
    const size_t HS = (size_t)B_ * U_ * sizeof(_Float16);   // 128 KB per plane
    _Float16* hi0 = (_Float16*)(ws + 4096);
    _Float16* lo0 = (_Float16*)(ws + 4096 + HS);
    _Float16* hi1 = (_Float16*)(ws + 4096 + 2*HS);
    _Float16* lo1 = (_Float16*)(ws + 4096 + 3*HS);

    hipMemsetAsync(ws, 0, 4096, stream);                 // barrier flags
    init_h<<<256, 256, 0, stream>>>(hidden, hi0, lo0);   // h_{-1} split
    xin_gemm<<<dim3(32, 16), 256, 0, stream>>>(x, emb, Wx, bias, out);
    rnn_scan<<<64, 256, 0, stream>>>(Wh, out, hi0, lo0, hi1, lo1, flags);
}

// Round 4
// 4993.626 us; speedup vs baseline: 1.0361x; 1.0361x over previous
//
#include <hip/hip_runtime.h>

// Encoder: x[B,T] int32, hidden[B,U], emb[V,E], Wx[E,U], Wh[U,U], b[U]  -- ALL FLOAT32
// out = concat( output[B,T,U], state[B,U] )  float32
// B=64 T=512 U=1024 E=256
// Precision: fp16 two-way split (hi + 2^11-scaled lo), 3 MFMA products.
// Sync protocol (this round): relaxed AGENT atomics only (sc1 write-through /
// L2-bypass reads) -- NO acquire/release fences, because agent-scope acquire
// emits buffer_inv (full L2 invalidate) per poll: that was the 9.6us/step.

#define B_ 64
#define T_ 512
#define U_ 1024
#define E_ 256
#define BTU_ (B_*T_*U_)
#define LO_SCALE 2048.0f
#define LO_INV   (1.0f/2048.0f)

typedef __attribute__((ext_vector_type(8))) _Float16 f16x8;  // MFMA A/B frag (4 VGPRs)
typedef __attribute__((ext_vector_type(4))) float f32x4;     // MFMA C/D frag

__device__ __forceinline__ void split16(float v, _Float16& hi, _Float16& lo) {
    hi = (_Float16)v;
    lo = (_Float16)((v - (float)hi) * LO_SCALE);   // scaled into fp16 normal range
}
__device__ __forceinline__ unsigned short h2u(_Float16 h) {
    union { _Float16 f; unsigned short u; } c; c.f = h; return c.u;
}

// ---------------------------------------------------------------------------
// init: split f32 hidden into fp16 hi / scaled-lo planes (h_{-1})
// ---------------------------------------------------------------------------
__global__ void init_h(const float* __restrict__ hidden,
                       _Float16* __restrict__ hi, _Float16* __restrict__ lo)
{
    const int i = blockIdx.x * 256 + threadIdx.x;   // 256 x 256 = B*U
    _Float16 h, l;
    split16(hidden[i], h, l);
    hi[i] = h; lo[i] = l;
}

// ---------------------------------------------------------------------------
// Phase 1: xin[m][u] = emb[x[m]][:] @ Wx + b  (m = b*T + t), f32 -> out[m*U+u]
// fp16-split MFMA (hh + cross/2048). Grid (32,16) x 256.
// ---------------------------------------------------------------------------
__global__ __launch_bounds__(256, 1) void xin_gemm(
    const int* __restrict__ x, const float* __restrict__ emb,
    const float* __restrict__ Wx, const float* __restrict__ bias,
    float* __restrict__ out)
{
    const int tid  = threadIdx.x;
    const int wave = tid >> 6, lane = tid & 63;
    const int quad = lane >> 4, l15 = lane & 15;
    const int nbase  = blockIdx.y * 64;
    const int mouter = blockIdx.x * 1024;

    f16x8 b1[4][8], b2[4][8];
#pragma unroll
    for (int nt = 0; nt < 4; ++nt) {
        const int col = nbase + nt*16 + l15;
#pragma unroll
        for (int ki = 0; ki < 8; ++ki) {
            const int kb = ki*32 + quad*8;
#pragma unroll
            for (int j = 0; j < 8; ++j) {
                _Float16 h, l;
                split16(Wx[(kb + j)*U_ + col], h, l);
                b1[nt][ki][j] = h; b2[nt][ki][j] = l;
            }
        }
    }
    float bv[4];
#pragma unroll
    for (int nt = 0; nt < 4; ++nt) bv[nt] = bias[nbase + nt*16 + l15];

    const f32x4 z4 = {0.f, 0.f, 0.f, 0.f};
    for (int mc = 0; mc < 8; ++mc) {
        const int mb0 = mouter + mc*128 + wave*32;
#pragma unroll
        for (int mt = 0; mt < 2; ++mt) {
            const int tok = x[mb0 + mt*16 + l15];
            const float* ap = emb + (size_t)tok*E_ + quad*8;
            f16x8 a1[8], a2[8];
#pragma unroll
            for (int ki = 0; ki < 8; ++ki) {
                const f32x4 v0 = *(const f32x4*)(ap + ki*32);
                const f32x4 v1 = *(const f32x4*)(ap + ki*32 + 4);
#pragma unroll
                for (int j = 0; j < 4; ++j) {
                    _Float16 h, l;
                    split16(v0[j], h, l); a1[ki][j]   = h; a2[ki][j]   = l;
                    split16(v1[j], h, l); a1[ki][j+4] = h; a2[ki][j+4] = l;
                }
            }
            f32x4 acc[4]  = {z4, z4, z4, z4};
            f32x4 accX[4] = {z4, z4, z4, z4};
#pragma unroll
            for (int ki = 0; ki < 8; ++ki)
#pragma unroll
                for (int nt = 0; nt < 4; ++nt) {
                    acc[nt]  = __builtin_amdgcn_mfma_f32_16x16x32_f16(a1[ki], b1[nt][ki], acc[nt], 0, 0, 0);
                    accX[nt] = __builtin_amdgcn_mfma_f32_16x16x32_f16(a1[ki], b2[nt][ki], accX[nt], 0, 0, 0);
                    accX[nt] = __builtin_amdgcn_mfma_f32_16x16x32_f16(a2[ki], b1[nt][ki], accX[nt], 0, 0, 0);
                }
            const int rowb = mb0 + mt*16 + quad*4;
#pragma unroll
            for (int nt = 0; nt < 4; ++nt) {
                const int col = nbase + nt*16 + l15;
#pragma unroll
                for (int r = 0; r < 4; ++r)
                    out[(size_t)(rowb + r)*U_ + col] = acc[nt][r] + LO_INV*accX[nt][r] + bv[nt];
            }
        }
    }
}

// ---------------------------------------------------------------------------
// Phase 2: persistent RNN scan, fp16-split recurrence.
// 4 batch-groups x 16 blocks (64 u-cols each). Wave w owns K-range [w*256,+256).
// Wh hi/lo frags persistent in VGPRs. Cross-block h exchange via relaxed
// agent-scope atomics (sc1) through the MALL; flags likewise. No fences.
// ---------------------------------------------------------------------------
__global__ __launch_bounds__(256, 1) void rnn_scan(
    const float* __restrict__ Wh,
    float* __restrict__ out,
    _Float16* __restrict__ hi0, _Float16* __restrict__ lo0,
    _Float16* __restrict__ hi1, _Float16* __restrict__ lo1,
    int* __restrict__ flags)
{
    const int tid  = threadIdx.x;
    const int w    = tid >> 6, lane = tid & 63;
    const int quad = lane >> 4, l15 = lane & 15;
    const int g    = blockIdx.x >> 4;    // batch group 0..3
    const int blk  = blockIdx.x & 15;    // column block 0..15
    const int bbase = g * 16;
    const int nb    = blk * 64;
    int* gflags = flags + g * 32;

    __shared__ __align__(16) float red[4][4][16][20];  // [wave][ntile][col][row(+pad)]

    // Persistent Wh fragments (split): k = w*256 + ki*32 + quad*8 + j, n = nb + nt*16 + l15
    f16x8 bh[4][8], bl[4][8];
#pragma unroll
    for (int nt = 0; nt < 4; ++nt) {
        const int col = nb + nt*16 + l15;
#pragma unroll
        for (int ki = 0; ki < 8; ++ki) {
            const int kb = w*256 + ki*32 + quad*8;
#pragma unroll
            for (int j = 0; j < 8; ++j) {
                _Float16 h, l;
                split16(Wh[(size_t)(kb + j)*U_ + col], h, l);
                bh[nt][ki][j] = h; bl[nt][ki][j] = l;
            }
        }
    }

    const int c  = tid >> 2;   // 0..63: column within block (combine phase)
    const int rq = tid & 3;    // row quad (combine phase)
    const int u  = nb + c;
    const f32x4 z4 = {0.f, 0.f, 0.f, 0.f};

    for (int t = 0; t < T_; ++t) {
        const _Float16* chi = (t & 1) ? hi1 : hi0;
        const _Float16* clo = (t & 1) ? lo1 : lo0;
        _Float16* nhi = (t & 1) ? hi0 : hi1;
        _Float16* nlo = (t & 1) ? lo0 : lo1;

        // A fragments via relaxed agent-scope (sc1, L2-bypass) dword loads
        const size_t abase = (size_t)(bbase + l15)*U_ + w*256 + quad*8;
        const unsigned int* chiW = (const unsigned int*)(chi + abase);
        const unsigned int* cloW = (const unsigned int*)(clo + abase);
        f16x8 ah[8], al[8];
#pragma unroll
        for (int ki = 0; ki < 8; ++ki) {
            union { unsigned int wd[4]; f16x8 v; } th, tl;
#pragma unroll
            for (int q = 0; q < 4; ++q) {
                th.wd[q] = __hip_atomic_load(chiW + ki*16 + q, __ATOMIC_RELAXED, __HIP_MEMORY_SCOPE_AGENT);
                tl.wd[q] = __hip_atomic_load(cloW + ki*16 + q, __ATOMIC_RELAXED, __HIP_MEMORY_SCOPE_AGENT);
            }
            ah[ki] = th.v; al[ki] = tl.v;
        }

        // Prefetch xin for this step (normal cached loads; latency hides under MFMA)
        float xin_pref[4];
#pragma unroll
        for (int j = 0; j < 4; ++j) {
            const int b = bbase + rq*4 + j;
            xin_pref[j] = out[((size_t)b*T_ + t)*U_ + u];
        }

        f32x4 acc[4]  = {z4, z4, z4, z4};
        f32x4 accX[4] = {z4, z4, z4, z4};
#pragma unroll
        for (int ki = 0; ki < 8; ++ki)
#pragma unroll
            for (int nt = 0; nt < 4; ++nt) {
                acc[nt]  = __builtin_amdgcn_mfma_f32_16x16x32_f16(ah[ki], bh[nt][ki], acc[nt], 0, 0, 0);
                accX[nt] = __builtin_amdgcn_mfma_f32_16x16x32_f16(ah[ki], bl[nt][ki], accX[nt], 0, 0, 0);
                accX[nt] = __builtin_amdgcn_mfma_f32_16x16x32_f16(al[ki], bh[nt][ki], accX[nt], 0, 0, 0);
            }

#pragma unroll
        for (int nt = 0; nt < 4; ++nt) {
            f32x4 s = acc[nt] + LO_INV*accX[nt];
            *(f32x4*)&red[w][nt][l15][quad*4] = s;
        }
        __syncthreads();

        // Combine 4 k-partials, add xin, tanh, store
        f32x4 s0 = *(const f32x4*)&red[0][c>>4][c&15][rq*4];
        f32x4 s1 = *(const f32x4*)&red[1][c>>4][c&15][rq*4];
        f32x4 s2 = *(const f32x4*)&red[2][c>>4][c&15][rq*4];
        f32x4 s3 = *(const f32x4*)&red[3][c>>4][c&15][rq*4];
        f32x4 ss = (s0 + s1) + (s2 + s3);
#pragma unroll
        for (int j = 0; j < 4; ++j) {
            const int b = bbase + rq*4 + j;
            const size_t xidx = ((size_t)b*T_ + t)*U_ + u;
            const float pre = xin_pref[j] + ss[j];
            const float h = tanhf(pre);
            out[xidx] = h;                                 // normal cached store
            _Float16 hh, hl;
            split16(h, hh, hl);
            const size_t hidx = (size_t)b*U_ + u;
            __hip_atomic_store((unsigned short*)&nhi[hidx], h2u(hh), __ATOMIC_RELAXED, __HIP_MEMORY_SCOPE_AGENT);
            __hip_atomic_store((unsigned short*)&nlo[hidx], h2u(hl), __ATOMIC_RELAXED, __HIP_MEMORY_SCOPE_AGENT);
            if (t == T_-1) out[(size_t)BTU_ + hidx] = h;   // final state
        }
        __syncthreads();   // drains vmcnt: sc1 h-stores complete at coherence point

        if (t < T_-1) {
            if (w == 0) {
                if (lane == 0)
                    __hip_atomic_store(&gflags[blk], t + 1, __ATOMIC_RELAXED, __HIP_MEMORY_SCOPE_AGENT);
                const int tgt = t + 1;
                for (;;) {
                    int v = __hip_atomic_load(&gflags[l15], __ATOMIC_RELAXED, __HIP_MEMORY_SCOPE_AGENT);
                    if (__all(v >= tgt)) break;
                    __builtin_amdgcn_s_sleep(1);
                }
            }
            __syncthreads();
        }
    }
}

extern "C" void kernel_launch(void* const* d_in, const int* in_sizes, int n_in,
                              void* d_out, int out_size, void* d_ws, size_t ws_size,
                              hipStream_t stream) {
    const int*   x      = (const int*)  d_in[0];
    const float* hidden = (const float*)d_in[1];
    const float* emb    = (const float*)d_in[2];
    const float* Wx     = (const float*)d_in[3];
    const float* Wh     = (const float*)d_in[4];
    const float* bias   = (const float*)d_in[5];
    float* out = (float*)d_out;

    char* ws = (char*)d_ws;
    int* flags = (int*)ws;                               // 4 groups x 32 ints
    const size_t HS = (size_t)B_ * U_ * sizeof(_Float16);   // 128 KB per plane
    _Float16* hi0 = (_Float16*)(ws + 4096);
    _Float16* lo0 = (_Float16*)(ws + 4096 + HS);
    _Float16* hi1 = (_Float16*)(ws + 4096 + 2*HS);
    _Float16* lo1 = (_Float16*)(ws + 4096 + 3*HS);

    hipMemsetAsync(ws, 0, 4096, stream);                 // barrier flags
    init_h<<<256, 256, 0, stream>>>(hidden, hi0, lo0);   // h_{-1} split
    xin_gemm<<<dim3(32, 16), 256, 0, stream>>>(x, emb, Wx, bias, out);
    rnn_scan<<<64, 256, 0, stream>>>(Wh, out, hi0, lo0, hi1, lo1, flags);
}